// Round 4
// baseline (2168.841 us; speedup 1.0000x reference)
//
#include <hip/hip_runtime.h>
#include <cstdint>
#include <cstddef>

// Problem constants (match reference setup_inputs)
#define NPTS 16384   // N
#define NSAMP 1024   // SAMPLES
#define KNBR 32      // MAX_NEIGHBORS
#define NCH 128      // C

// ---------------------------------------------------------------------------
// ROUND-7 THEORY:
// (a) R3 counters (VALUBusy x0.87 not x0.67; VGPR_Count stuck at 96 < the
//     128-reg live state) => clang scalarized the f32x2 math and is not
//     keeping coords fully resident. Fix: inline-asm v_pk_add_f32/v_pk_mul_f32
//     (VOP3P) on f32x2 pairs; sub via neg_lo/neg_hi. Elementwise IEEE =>
//     bit-exact; asm operands force register residency.
// (b) group work (~120us) is fully hidden under fps: single fused kernel;
//     B fps blocks + B*16 group blocks (8 waves x 8 centroids). Producer/
//     consumer via relaxed AGENT-scope atomics (HW-validated rounds 4-5):
//     fps t0 atomically stores co[s]; the compiler's s_waitcnt vmcnt(0)
//     before the next iteration's s_barrier drains them to the coherence
//     point; after that barrier t0 publishes progress[b]=s. Consumers poll
//     progress (relaxed + s_sleep backoff) and read co via relaxed-agent
//     atomic loads (bypasses stale local cache lines - 5 centroids share a
//     64B line, plain loads would be a staleness bug). Deadlock-safe by
//     capacity: 68 blocks all co-resident (1 block/CU at waves_per_eu(2,2)),
//     no dispatch-order assumption; bounded polls = terminate-don't-hang.
//
// Exactness contract (absmax 0): d = (dx*dx+dy*dy)+dz*dz, no FMA, pk ops are
// elementwise IEEE; md = fminf(md, d); argmax tie-break smallest global
// index (in-pair strict > picks .x; running strict > keeps earlier pair;
// cross-lane/wave via u64 key (f32bits<<32)|~idx).
// ---------------------------------------------------------------------------

#define FPS_TPB 512
#define PROG_STRIDE 32  // u32s per batch progress word (one 128B line each)

typedef float f32x2 __attribute__((ext_vector_type(2)));

#define PR16_FOREACH(X) \
  X(0) X(1) X(2) X(3) X(4) X(5) X(6) X(7) \
  X(8) X(9) X(10) X(11) X(12) X(13) X(14) X(15)

__global__ void init_progress(unsigned* __restrict__ p, int n) {
  const int i = blockIdx.x * blockDim.x + threadIdx.x;
  if (i < n) p[i] = 0u;
}

__global__ __launch_bounds__(FPS_TPB)
__attribute__((amdgpu_waves_per_eu(2, 2)))
void fused_kernel(const float* __restrict__ xyz, const float* __restrict__ feat,
                  float* __restrict__ centroids, float* __restrict__ gxyz,
                  float* __restrict__ gfeat, unsigned* __restrict__ progress,
                  int B) {
#pragma clang fp contract(off)
  // LDS union across roles (roles are per-block, so no aliasing hazards)
  __shared__ unsigned long long s_wkey[2][FPS_TPB / 64];
  __shared__ int sh_idx[8][KNBR];
  __shared__ float sh_gx[8][KNBR * 3];

  if ((int)blockIdx.x < B) {
    // ===================== FPS role (blocks 0..B-1) ========================
    const int b = blockIdx.x;
    const int t = threadIdx.x;
    const float* __restrict__ px = xyz + (size_t)b * NPTS * 3;
    float* co = centroids + (size_t)b * NSAMP * 3;
    unsigned* prog = progress + b * PROG_STRIDE;

#define DECL_PR(j) f32x2 X##j, Y##j, Z##j, M##j;
    PR16_FOREACH(DECL_PR)
#undef DECL_PR

#define LOAD_PR(j)                                  \
    {                                               \
      const int pa = (2 * (j)) * FPS_TPB + t;       \
      const int pb = pa + FPS_TPB;                  \
      X##j.x = px[pa * 3 + 0];                      \
      Y##j.x = px[pa * 3 + 1];                      \
      Z##j.x = px[pa * 3 + 2];                      \
      X##j.y = px[pb * 3 + 0];                      \
      Y##j.y = px[pb * 3 + 1];                      \
      Z##j.y = px[pb * 3 + 2];                      \
      M##j = {1e10f, 1e10f};                        \
    }
    PR16_FOREACH(LOAD_PR)
#undef LOAD_PR

    float lx = px[0], ly = px[1], lz = px[2];
    if (t == 0) {
      // atomic relaxed agent stores: visible at the device coherence point
      __hip_atomic_store((unsigned*)&co[0], __float_as_uint(lx),
                         __ATOMIC_RELAXED, __HIP_MEMORY_SCOPE_AGENT);
      __hip_atomic_store((unsigned*)&co[1], __float_as_uint(ly),
                         __ATOMIC_RELAXED, __HIP_MEMORY_SCOPE_AGENT);
      __hip_atomic_store((unsigned*)&co[2], __float_as_uint(lz),
                         __ATOMIC_RELAXED, __HIP_MEMORY_SCOPE_AGENT);
    }

    for (int s = 1; s < NSAMP; ++s) {
      const int par = s & 1;
      const f32x2 cx = {lx, lx};
      const f32x2 cy = {ly, ly};
      const f32x2 cz = {lz, lz};

      float bv = -1.0f;
      int bs = 0;
#define UPD_PR(j)                                                         \
      {                                                                   \
        f32x2 dx, dy, dz, sx, sy, sz, s1, s2;                             \
        asm("v_pk_add_f32 %0, %1, %2 neg_lo:[0,1] neg_hi:[0,1]"           \
            : "=v"(dx) : "v"(X##j), "v"(cx));                             \
        asm("v_pk_add_f32 %0, %1, %2 neg_lo:[0,1] neg_hi:[0,1]"           \
            : "=v"(dy) : "v"(Y##j), "v"(cy));                             \
        asm("v_pk_add_f32 %0, %1, %2 neg_lo:[0,1] neg_hi:[0,1]"           \
            : "=v"(dz) : "v"(Z##j), "v"(cz));                             \
        asm("v_pk_mul_f32 %0, %1, %1" : "=v"(sx) : "v"(dx));              \
        asm("v_pk_mul_f32 %0, %1, %1" : "=v"(sy) : "v"(dy));              \
        asm("v_pk_mul_f32 %0, %1, %1" : "=v"(sz) : "v"(dz));              \
        asm("v_pk_add_f32 %0, %1, %2" : "=v"(s1) : "v"(sx), "v"(sy));     \
        asm("v_pk_add_f32 %0, %1, %2" : "=v"(s2) : "v"(s1), "v"(sz));     \
        M##j.x = fminf(M##j.x, s2.x);                                     \
        M##j.y = fminf(M##j.y, s2.y);                                     \
        float vj; int sj;                                                 \
        if (M##j.y > M##j.x) { vj = M##j.y; sj = 2 * (j) + 1; }           \
        else                 { vj = M##j.x; sj = 2 * (j); }               \
        if (vj > bv) { bv = vj; bs = sj; }  /* strict >: min index */     \
      }
      PR16_FOREACH(UPD_PR)
#undef UPD_PR

      const unsigned int bi = ((unsigned int)bs << 9) | (unsigned int)t;
      unsigned long long key =
          ((unsigned long long)__float_as_uint(bv) << 32) |
          (unsigned int)(~bi);

#pragma unroll
      for (int off = 1; off < 64; off <<= 1) {
        const unsigned long long ok = __shfl_xor(key, off);
        if (ok > key) key = ok;
      }
      if ((t & 63) == 0) s_wkey[par][t >> 6] = key;
      __syncthreads();  // compiler emits vmcnt(0) drain: co[s-1] now at LLC

      // publish progress AFTER the drain: co[0..s-1] are globally visible
      if (t == 0)
        __hip_atomic_store(prog, (unsigned)s, __ATOMIC_RELAXED,
                           __HIP_MEMORY_SCOPE_AGENT);

      unsigned long long best = s_wkey[par][0];
#pragma unroll
      for (int w = 1; w < FPS_TPB / 64; ++w) {
        const unsigned long long k2 = s_wkey[par][w];
        if (k2 > best) best = k2;
      }
      const unsigned int widx = (unsigned int)__builtin_amdgcn_readfirstlane(
          (int)(~(unsigned int)best));

      lx = px[widx * 3 + 0];
      ly = px[widx * 3 + 1];
      lz = px[widx * 3 + 2];
      if (t == 0) {
        __hip_atomic_store((unsigned*)&co[s * 3 + 0], __float_as_uint(lx),
                           __ATOMIC_RELAXED, __HIP_MEMORY_SCOPE_AGENT);
        __hip_atomic_store((unsigned*)&co[s * 3 + 1], __float_as_uint(ly),
                           __ATOMIC_RELAXED, __HIP_MEMORY_SCOPE_AGENT);
        __hip_atomic_store((unsigned*)&co[s * 3 + 2], __float_as_uint(lz),
                           __ATOMIC_RELAXED, __HIP_MEMORY_SCOPE_AGENT);
      }
    }
    __syncthreads();  // drain co[1023]
    if (t == 0)
      __hip_atomic_store(prog, (unsigned)NSAMP, __ATOMIC_RELAXED,
                         __HIP_MEMORY_SCOPE_AGENT);
  } else {
    // ===================== group role (B*16 blocks) ========================
    const int gi = blockIdx.x - B;
    const int wave = threadIdx.x >> 6;
    const int lane = threadIdx.x & 63;
    const int w = gi * 8 + wave;   // 0 .. B*128-1
    const int WPB = B * 128;
    const float rr = 0.04f;  // float32(0.04), NOT 0.2f*0.2f (1 ulp larger)

    for (int i = 0; i < 8; ++i) {
      const int gw = w + WPB * i;        // 0 .. B*1024-1
      const int b = gw >> 10;
      const int s = gw & 1023;
      unsigned* prog = progress + b * PROG_STRIDE;

      // wait until centroid s is published (progress > s). bounded: never hang
      unsigned pr = __hip_atomic_load(prog, __ATOMIC_RELAXED,
                                      __HIP_MEMORY_SCOPE_AGENT);
      int g = 0;
      while (pr < (unsigned)(s + 1) && g < (1 << 20)) {
        __builtin_amdgcn_s_sleep(16);
        pr = __hip_atomic_load(prog, __ATOMIC_RELAXED,
                               __HIP_MEMORY_SCOPE_AGENT);
        ++g;
      }

      const float* px = xyz + (size_t)b * NPTS * 3;
      const float* pc = centroids + (size_t)gw * 3;
      // atomic relaxed agent loads: read from coherence point (5 centroids
      // share a 64B line -> plain loads could hit a stale local cache line)
      const float cx = __uint_as_float(__hip_atomic_load(
          (const unsigned*)&pc[0], __ATOMIC_RELAXED, __HIP_MEMORY_SCOPE_AGENT));
      const float cy = __uint_as_float(__hip_atomic_load(
          (const unsigned*)&pc[1], __ATOMIC_RELAXED, __HIP_MEMORY_SCOPE_AGENT));
      const float cz = __uint_as_float(__hip_atomic_load(
          (const unsigned*)&pc[2], __ATOMIC_RELAXED, __HIP_MEMORY_SCOPE_AGENT));

      int cnt = 0;
      for (int n0 = 0; n0 < NPTS && cnt < KNBR; n0 += 64) {
        const int p = n0 + lane;
        const float xx = px[p * 3 + 0];
        const float yy = px[p * 3 + 1];
        const float zz = px[p * 3 + 2];
        const float dx = xx - cx;
        const float dy = yy - cy;
        const float dz = zz - cz;
        const float d = (dx * dx + dy * dy) + dz * dz;  // no FMA
        const bool in = d <= rr;
        const unsigned long long mask = __ballot(in);
        const int pos = cnt + (int)__popcll(mask & ((1ull << lane) - 1ull));
        if (in && pos < KNBR) {
          sh_idx[wave][pos] = p;
          sh_gx[wave][pos * 3 + 0] = dx;
          sh_gx[wave][pos * 3 + 1] = dy;
          sh_gx[wave][pos * 3 + 2] = dz;
        }
        cnt += (int)__popcll(mask);
      }
      if (cnt == 0 && lane == 0) {  // safety: cannot happen
        sh_idx[wave][0] = 0;
        sh_gx[wave][0] = px[0] - cx;
        sh_gx[wave][1] = px[1] - cy;
        sh_gx[wave][2] = px[2] - cz;
      }
      const int nf0 = (cnt < 1) ? 1 : cnt;
      const int nf = (nf0 < KNBR) ? nf0 : KNBR;
      __syncthreads();  // uniform count: every wave runs exactly 8 iterations
      if (lane < KNBR && lane >= nf) {
        sh_idx[wave][lane] = sh_idx[wave][0];
        sh_gx[wave][lane * 3 + 0] = sh_gx[wave][0];
        sh_gx[wave][lane * 3 + 1] = sh_gx[wave][1];
        sh_gx[wave][lane * 3 + 2] = sh_gx[wave][2];
      }
      __syncthreads();

      float* ox = gxyz + (size_t)gw * KNBR * 3;
      const float* shf = sh_gx[wave];
      for (int j = lane; j < KNBR * 3; j += 64) ox[j] = shf[j];

      float* og = gfeat + (size_t)gw * KNBR * NCH;
      const float* pf = feat + (size_t)b * NPTS * NCH;
#pragma unroll 4
      for (int k = 0; k < KNBR; ++k) {
        const int row = sh_idx[wave][k];
        const float2 v = ((const float2*)(pf + (size_t)row * NCH))[lane];
        ((float2*)(og + (size_t)k * NCH))[lane] = v;
      }
    }
  }
}

// ---------------------------------------------------------------------------
// Fallback path (ws too small): round-3 kernels, known-good.
// ---------------------------------------------------------------------------
__global__ __launch_bounds__(FPS_TPB)
__attribute__((amdgpu_waves_per_eu(2, 2)))
void fps_kernel(
    const float* __restrict__ xyz, float* __restrict__ centroids) {
#pragma clang fp contract(off)
  const int b = blockIdx.x;
  const int t = threadIdx.x;
  const float* __restrict__ px = xyz + (size_t)b * NPTS * 3;

#define DECL_PR(j) f32x2 X##j, Y##j, Z##j, M##j;
  PR16_FOREACH(DECL_PR)
#undef DECL_PR
#define LOAD_PR(j)                                  \
  {                                                 \
    const int pa = (2 * (j)) * FPS_TPB + t;         \
    const int pb = pa + FPS_TPB;                    \
    X##j.x = px[pa * 3 + 0];                        \
    Y##j.x = px[pa * 3 + 1];                        \
    Z##j.x = px[pa * 3 + 2];                        \
    X##j.y = px[pb * 3 + 0];                        \
    Y##j.y = px[pb * 3 + 1];                        \
    Z##j.y = px[pb * 3 + 2];                        \
    M##j = {1e10f, 1e10f};                          \
  }
  PR16_FOREACH(LOAD_PR)
#undef LOAD_PR

  __shared__ unsigned long long s_wkey[2][FPS_TPB / 64];
  float* co = centroids + (size_t)b * NSAMP * 3;
  float lx = px[0], ly = px[1], lz = px[2];
  if (t == 0) { co[0] = lx; co[1] = ly; co[2] = lz; }

  for (int s = 1; s < NSAMP; ++s) {
    const int par = s & 1;
    const f32x2 cx = {lx, lx};
    const f32x2 cy = {ly, ly};
    const f32x2 cz = {lz, lz};
    float bv = -1.0f;
    int bs = 0;
#define UPD_PR(j)                                                       \
    {                                                                   \
      f32x2 dx = X##j - cx, dy = Y##j - cy, dz = Z##j - cz;             \
      f32x2 dd = (dx * dx + dy * dy) + dz * dz;                         \
      M##j.x = fminf(M##j.x, dd.x);                                     \
      M##j.y = fminf(M##j.y, dd.y);                                     \
      float vj; int sj;                                                 \
      if (M##j.y > M##j.x) { vj = M##j.y; sj = 2 * (j) + 1; }           \
      else                 { vj = M##j.x; sj = 2 * (j); }               \
      if (vj > bv) { bv = vj; bs = sj; }                                \
    }
    PR16_FOREACH(UPD_PR)
#undef UPD_PR
    const unsigned int bi = ((unsigned int)bs << 9) | (unsigned int)t;
    unsigned long long key =
        ((unsigned long long)__float_as_uint(bv) << 32) |
        (unsigned int)(~bi);
#pragma unroll
    for (int off = 1; off < 64; off <<= 1) {
      const unsigned long long ok = __shfl_xor(key, off);
      if (ok > key) key = ok;
    }
    if ((t & 63) == 0) s_wkey[par][t >> 6] = key;
    __syncthreads();
    unsigned long long best = s_wkey[par][0];
#pragma unroll
    for (int w = 1; w < FPS_TPB / 64; ++w) {
      const unsigned long long k2 = s_wkey[par][w];
      if (k2 > best) best = k2;
    }
    const unsigned int widx = (unsigned int)__builtin_amdgcn_readfirstlane(
        (int)(~(unsigned int)best));
    lx = px[widx * 3 + 0];
    ly = px[widx * 3 + 1];
    lz = px[widx * 3 + 2];
    if (t == 0) {
      co[s * 3 + 0] = lx;
      co[s * 3 + 1] = ly;
      co[s * 3 + 2] = lz;
    }
  }
}

__global__ __launch_bounds__(256) void group_kernel(
    const float* __restrict__ xyz, const float* __restrict__ feat,
    const float* __restrict__ centroids,
    float* __restrict__ gxyz, float* __restrict__ gfeat) {
#pragma clang fp contract(off)
  const int wave = threadIdx.x >> 6;
  const int lane = threadIdx.x & 63;
  const int gw = blockIdx.x * 4 + wave;
  const int b = gw >> 10;
  const float* px = xyz + (size_t)b * NPTS * 3;
  const float* pc = centroids + (size_t)gw * 3;
  const float cx = pc[0], cy = pc[1], cz = pc[2];
  const float rr = 0.04f;

  __shared__ int sh_idx[4][KNBR];
  __shared__ float sh_gx[4][KNBR * 3];

  int cnt = 0;
  for (int n0 = 0; n0 < NPTS && cnt < KNBR; n0 += 64) {
    const int p = n0 + lane;
    const float xx = px[p * 3 + 0];
    const float yy = px[p * 3 + 1];
    const float zz = px[p * 3 + 2];
    const float dx = xx - cx;
    const float dy = yy - cy;
    const float dz = zz - cz;
    const float d = (dx * dx + dy * dy) + dz * dz;
    const bool in = d <= rr;
    const unsigned long long mask = __ballot(in);
    const int pos = cnt + (int)__popcll(mask & ((1ull << lane) - 1ull));
    if (in && pos < KNBR) {
      sh_idx[wave][pos] = p;
      sh_gx[wave][pos * 3 + 0] = dx;
      sh_gx[wave][pos * 3 + 1] = dy;
      sh_gx[wave][pos * 3 + 2] = dz;
    }
    cnt += (int)__popcll(mask);
  }
  if (cnt == 0 && lane == 0) {
    sh_idx[wave][0] = 0;
    sh_gx[wave][0] = px[0] - cx;
    sh_gx[wave][1] = px[1] - cy;
    sh_gx[wave][2] = px[2] - cz;
  }
  const int nf0 = (cnt < 1) ? 1 : cnt;
  const int nf = (nf0 < KNBR) ? nf0 : KNBR;
  __syncthreads();
  if (lane < KNBR && lane >= nf) {
    sh_idx[wave][lane] = sh_idx[wave][0];
    sh_gx[wave][lane * 3 + 0] = sh_gx[wave][0];
    sh_gx[wave][lane * 3 + 1] = sh_gx[wave][1];
    sh_gx[wave][lane * 3 + 2] = sh_gx[wave][2];
  }
  __syncthreads();
  float* ox = gxyz + (size_t)gw * KNBR * 3;
  const float* shf = sh_gx[wave];
  for (int j = lane; j < KNBR * 3; j += 64) ox[j] = shf[j];
  float* og = gfeat + (size_t)gw * KNBR * NCH;
  const float* pf = feat + (size_t)b * NPTS * NCH;
#pragma unroll 4
  for (int k = 0; k < KNBR; ++k) {
    const int row = sh_idx[wave][k];
    const float2 v = ((const float2*)(pf + (size_t)row * NCH))[lane];
    ((float2*)(og + (size_t)k * NCH))[lane] = v;
  }
}

extern "C" void kernel_launch(void* const* d_in, const int* in_sizes, int n_in,
                              void* d_out, int out_size, void* d_ws, size_t ws_size,
                              hipStream_t stream) {
  const float* xyz = (const float*)d_in[0];
  const float* feat = (const float*)d_in[1];
  float* out = (float*)d_out;
  const int B = in_sizes[0] / (NPTS * 3);

  float* centroids = out;                                   // [B,S,3]
  float* gxyz = centroids + (size_t)B * NSAMP * 3;          // [B,S,K,3]
  float* gfeat = gxyz + (size_t)B * NSAMP * KNBR * 3;       // [B,S,K,C]

  const int nprog = B * PROG_STRIDE;
  const size_t need = (size_t)nprog * sizeof(unsigned);
  if (d_ws != nullptr && ws_size >= need) {
    unsigned* progress = (unsigned*)d_ws;
    init_progress<<<(nprog + 127) / 128, 128, 0, stream>>>(progress, nprog);
    // grid: B fps blocks + B*16 group blocks (all co-resident by capacity)
    fused_kernel<<<B * 17, FPS_TPB, 0, stream>>>(xyz, feat, centroids, gxyz,
                                                 gfeat, progress, B);
  } else {
    fps_kernel<<<B, FPS_TPB, 0, stream>>>(xyz, centroids);
    group_kernel<<<(B * NSAMP) / 4, 256, 0, stream>>>(xyz, feat, centroids,
                                                      gxyz, gfeat);
  }
}

// Round 6
// 1999.798 us; speedup vs baseline: 1.0845x; 1.0845x over previous
//
#include <hip/hip_runtime.h>
#include <cstdint>
#include <cstddef>

// Problem constants (match reference setup_inputs)
#define NPTS 16384   // N
#define NSAMP 1024   // SAMPLES
#define KNBR 32      // MAX_NEIGHBORS
#define NCH 128      // C

// ---------------------------------------------------------------------------
// ROUND-9: resubmission of round-8 kernel (bench infra failed: "container
// failed twice", no compile/correctness signal; kernel has no spin loops or
// atomic protocols that could hang -> transient).
//
// ROUND-8 THEORY: R0-R4 evidence: single-block FPS is VALU-issue-bound and
// ~40% of issue is REMATERIALIZATION (allocator refuses to hold 128 coord
// regs at 512thr/32pt; VGPR stuck 88-96 across all rounds; waves_per_eu(2,2)
// did not pin it; inline-asm pk math didn't either - VGPR 92). Fix the
// decomposition instead of fighting the allocator: 1024 threads x 16 pts.
// Live state ~90 VGPR fits under the 128-reg cap that a 1024-thread block
// forces anyway (4 waves/SIMD), so residency is free. waves_per_eu(4,4)
// pins the target. Cross-wave reduce for 16 waves: lane reads key[lane&15],
// 4-step xor butterfly, readfirstlane.
//
// R4 lessons: fusion is a net loss (vmcnt(0) drain before each barrier
// serializes the atomic co/progress stores into the loop, +400us) -> unfused.
// group_kernel was 6x off its write-BW floor (66MB -> 10.5us; measured 120us)
// due to 1 wave serially gathering 32 rows -> one block per centroid, wave 0
// scans, all 4 waves gather 8 rows each.
//
// Exactness contract (absmax 0): d = (dx*dx+dy*dy)+dz*dz with contract(off)
// (no FMA; f32x2 ops elementwise IEEE whether packed or scalarized),
// md = fminf(md, d). Argmax tie-break smallest global index: p = slot*1024+t,
// bi = (slot<<10)|t == p; in-pair strict > picks .x (smaller slot) on ties;
// running strict > keeps earlier pair; cross-lane/wave via u64 key
// (f32bits(val)<<32)|~bi -- min-dists >= 0 so f32 bits are u32-monotone,
// ~bi makes larger key == smaller index on value ties.
// ---------------------------------------------------------------------------

#define FPS_TPB 1024
#define FPS_WAVES (FPS_TPB / 64)   // 16

typedef float f32x2 __attribute__((ext_vector_type(2)));

#define PR8_FOREACH(X) X(0) X(1) X(2) X(3) X(4) X(5) X(6) X(7)

__global__ __launch_bounds__(FPS_TPB)
__attribute__((amdgpu_waves_per_eu(4, 4)))  // pin allocator: 128-VGPR budget
void fps_kernel(
    const float* __restrict__ xyz, float* __restrict__ centroids) {
#pragma clang fp contract(off)
  const int b = blockIdx.x;
  const int t = threadIdx.x;          // 0..1023
  const int lane = t & 63;
  const int wave = t >> 6;            // 0..15
  const float* __restrict__ px = xyz + (size_t)b * NPTS * 3;

#define DECL_PR(j) f32x2 X##j, Y##j, Z##j, M##j;
  PR8_FOREACH(DECL_PR)
#undef DECL_PR

  // pair j covers slots (2j, 2j+1); point p = slot*1024 + t (coalesced)
#define LOAD_PR(j)                                  \
  {                                                 \
    const int pa = (2 * (j)) * FPS_TPB + t;         \
    const int pb = pa + FPS_TPB;                    \
    X##j.x = px[pa * 3 + 0];                        \
    Y##j.x = px[pa * 3 + 1];                        \
    Z##j.x = px[pa * 3 + 2];                        \
    X##j.y = px[pb * 3 + 0];                        \
    Y##j.y = px[pb * 3 + 1];                        \
    Z##j.y = px[pb * 3 + 2];                        \
    M##j = {1e10f, 1e10f};                          \
  }
  PR8_FOREACH(LOAD_PR)
#undef LOAD_PR

  __shared__ unsigned long long s_wkey[2][FPS_WAVES];  // parity dbuf

  float* co = centroids + (size_t)b * NSAMP * 3;
  float lx = px[0], ly = px[1], lz = px[2];
  if (t == 0) { co[0] = lx; co[1] = ly; co[2] = lz; }

  for (int s = 1; s < NSAMP; ++s) {
    const int par = s & 1;
    const f32x2 cx = {lx, lx};
    const f32x2 cy = {ly, ly};
    const f32x2 cz = {lz, lz};

    float bv = -1.0f;
    int bs = 0;  // best slot 0..15 (compile-time consts feed cndmask)
#define UPD_PR(j)                                                       \
    {                                                                   \
      f32x2 dx = X##j - cx, dy = Y##j - cy, dz = Z##j - cz;             \
      f32x2 dd = (dx * dx + dy * dy) + dz * dz; /* no FMA */            \
      M##j.x = fminf(M##j.x, dd.x);                                     \
      M##j.y = fminf(M##j.y, dd.y);                                     \
      float vj; int sj;                                                 \
      if (M##j.y > M##j.x) { vj = M##j.y; sj = 2 * (j) + 1; }           \
      else                 { vj = M##j.x; sj = 2 * (j); }               \
      if (vj > bv) { bv = vj; bs = sj; }  /* strict >: min index */     \
    }
    PR8_FOREACH(UPD_PR)
#undef UPD_PR

    const unsigned int bi = ((unsigned int)bs << 10) | (unsigned int)t;
    unsigned long long key =
        ((unsigned long long)__float_as_uint(bv) << 32) |
        (unsigned int)(~bi);

    // intra-wave butterfly max (6 steps over 64 lanes)
#pragma unroll
    for (int off = 1; off < 64; off <<= 1) {
      const unsigned long long ok = __shfl_xor(key, off);
      if (ok > key) key = ok;
    }
    if (lane == 0) s_wkey[par][wave] = key;
    __syncthreads();  // the ONLY barrier per iteration (parity dbuf)

    // cross-wave reduce: each lane reads one of the 16 wave keys, 4-step
    // xor butterfly within each 16-lane group -> all lanes hold block max
    unsigned long long best = s_wkey[par][lane & 15];
#pragma unroll
    for (int off = 1; off < 16; off <<= 1) {
      const unsigned long long ok = __shfl_xor(best, off);
      if (ok > best) best = ok;
    }
    // uniform across block by construction; readfirstlane -> scalar load
    const unsigned int widx = (unsigned int)__builtin_amdgcn_readfirstlane(
        (int)(~(unsigned int)best));

    lx = px[widx * 3 + 0];
    ly = px[widx * 3 + 1];
    lz = px[widx * 3 + 2];
    if (t == 0) {
      co[s * 3 + 0] = lx;
      co[s * 3 + 1] = ly;
      co[s * 3 + 2] = lz;
    }
  }
}

// ---------------------------------------------------------------------------
// Kernel 2: ball query + gather. ONE BLOCK PER CENTROID (4096 blocks, ~16/CU
// of TLP). Wave 0 runs the ordered ballot scan (identical arithmetic to the
// round-0-validated version -> bit-exact); after a barrier all 4 waves gather
// 8 feature rows each (float2/lane = full 512B row per wave-instr).
// ---------------------------------------------------------------------------
__global__ __launch_bounds__(256) void group_kernel(
    const float* __restrict__ xyz, const float* __restrict__ feat,
    const float* __restrict__ centroids,
    float* __restrict__ gxyz, float* __restrict__ gfeat) {
#pragma clang fp contract(off)
  const int gw = blockIdx.x;            // == b * NSAMP + s
  const int b = gw >> 10;
  const int wave = threadIdx.x >> 6;
  const int lane = threadIdx.x & 63;

  const float* px = xyz + (size_t)b * NPTS * 3;
  const float* pc = centroids + (size_t)gw * 3;
  const float cx = pc[0], cy = pc[1], cz = pc[2];
  // float32(0.04): numpy compares f32 sqd against python-double 0.04 demoted
  // to f32. NOT 0.2f*0.2f (that's a different float, 1 ulp larger).
  const float rr = 0.04f;

  __shared__ int sh_idx[KNBR];
  __shared__ float sh_gx[KNBR * 3];
  __shared__ int sh_cnt;

  if (wave == 0) {
    int cnt = 0;
    for (int n0 = 0; n0 < NPTS && cnt < KNBR; n0 += 64) {
      const int p = n0 + lane;
      const float xx = px[p * 3 + 0];
      const float yy = px[p * 3 + 1];
      const float zz = px[p * 3 + 2];
      const float dx = xx - cx;
      const float dy = yy - cy;
      const float dz = zz - cz;
      const float d = (dx * dx + dy * dy) + dz * dz;  // contract(off): no FMA
      const bool in = d <= rr;
      const unsigned long long mask = __ballot(in);
      const int pos = cnt + (int)__popcll(mask & ((1ull << lane) - 1ull));
      if (in && pos < KNBR) {
        sh_idx[pos] = p;
        sh_gx[pos * 3 + 0] = dx;
        sh_gx[pos * 3 + 1] = dy;
        sh_gx[pos * 3 + 2] = dz;
      }
      cnt += (int)__popcll(mask);
    }
    // Safety: cannot happen (centroid is itself in-ball), but avoid garbage
    // indices if it somehow does.
    if (cnt == 0 && lane == 0) {
      sh_idx[0] = 0;
      sh_gx[0] = px[0] - cx;
      sh_gx[1] = px[1] - cy;
      sh_gx[2] = px[2] - cz;
    }
    if (lane == 0) sh_cnt = (cnt < 1) ? 1 : cnt;
  }
  __syncthreads();

  // pad slots [nf, K) with the first hit (matches reference padding)
  const int nf = (sh_cnt < KNBR) ? sh_cnt : KNBR;
  if ((int)threadIdx.x < KNBR && (int)threadIdx.x >= nf) {
    sh_idx[threadIdx.x] = sh_idx[0];
    sh_gx[threadIdx.x * 3 + 0] = sh_gx[0];
    sh_gx[threadIdx.x * 3 + 1] = sh_gx[1];
    sh_gx[threadIdx.x * 3 + 2] = sh_gx[2];
  }
  __syncthreads();

  // grouped_xyz: 96 floats (threads 0..95, one shot)
  float* ox = gxyz + (size_t)gw * KNBR * 3;
  if (threadIdx.x < KNBR * 3) ox[threadIdx.x] = sh_gx[threadIdx.x];

  // gather features: each wave handles 8 rows; float2/lane = 512B row
  float* og = gfeat + (size_t)gw * KNBR * NCH;
  const float* pf = feat + (size_t)b * NPTS * NCH;
#pragma unroll
  for (int k = wave; k < KNBR; k += 4) {
    const int row = sh_idx[k];
    const float2 v = ((const float2*)(pf + (size_t)row * NCH))[lane];
    ((float2*)(og + (size_t)k * NCH))[lane] = v;
  }
}

extern "C" void kernel_launch(void* const* d_in, const int* in_sizes, int n_in,
                              void* d_out, int out_size, void* d_ws, size_t ws_size,
                              hipStream_t stream) {
  const float* xyz = (const float*)d_in[0];
  const float* feat = (const float*)d_in[1];
  float* out = (float*)d_out;
  const int B = in_sizes[0] / (NPTS * 3);

  float* centroids = out;                                   // [B,S,3]
  float* gxyz = centroids + (size_t)B * NSAMP * 3;          // [B,S,K,3]
  float* gfeat = gxyz + (size_t)B * NSAMP * KNBR * 3;       // [B,S,K,C]

  fps_kernel<<<B, FPS_TPB, 0, stream>>>(xyz, centroids);
  group_kernel<<<B * NSAMP, 256, 0, stream>>>(xyz, feat, centroids, gxyz,
                                              gfeat);
}